// Round 1
// baseline (65.491 us; speedup 1.0000x reference)
//
#include <hip/hip_runtime.h>

// Problem constants (match reference.py)
constexpr int N = 4096;   // points
constexpr int M = 1024;   // queries
constexpr int C = 64;     // channels
constexpr int WAVES = 4;              // waves per block (block = 64 x 4)
constexpr int ITERS = N / (64 * WAVES);  // 16 mask iterations per wave
#define HALF_KW 0.05f     // kernel_size/2, strict '<' per reference
#define NEG_INF (-3.402823466e38f)   // jnp.finfo(float32).min == -FLT_MAX

// One block per query. lane (threadIdx.x, 0..63) = channel. threadIdx.y = wave id.
// Phase 1: each wave ballots the in-box mask for its 1024 points (16 iters,
//          fully unrolled so all 16 coord float2 loads are in flight at once).
// Phase 2: uniform scalar-loop over set bits; each hit is one coalesced
//          256B values load + fmaxf. ~41 hits/query total across 4 waves.
// Phase 3: 4-way cross-wave max via LDS.
__global__ __launch_bounds__(256) void maxpool_box_kernel(
    const float* __restrict__ values,    // [N, C]
    const float* __restrict__ coords,    // [N, 2]
    const float* __restrict__ qcoords,   // [M, 2]
    float* __restrict__ out)             // [M, C]
{
    const int q    = blockIdx.x;
    const int lane = threadIdx.x;   // channel
    const int w    = threadIdx.y;   // wave id 0..3

    const float qx = qcoords[2 * q + 0];
    const float qy = qcoords[2 * q + 1];

    // ---- Phase 1: build 16 ballot masks (wave-uniform, live in SGPR pairs) ----
    unsigned long long masks[ITERS];
    #pragma unroll
    for (int i = 0; i < ITERS; ++i) {
        const int j = w * 64 + i * (64 * WAVES) + lane;           // point index
        const float2 c = ((const float2*)coords)[j];              // coalesced 8B/lane
        const bool in = (fabsf(qx - c.x) < HALF_KW) &&
                        (fabsf(qy - c.y) < HALF_KW);
        masks[i] = __ballot(in);                                  // 64-bit on CDNA
    }

    // ---- Phase 2: gather matched points, per-channel max ----
    float acc = NEG_INF;
    #pragma unroll 1
    for (int i = 0; i < ITERS; ++i) {
        unsigned long long m = masks[i];
        const int base = w * 64 + i * (64 * WAVES);
        while (m) {                       // uniform loop: m is wave-uniform
            const int bit = __ffsll((unsigned long long)m) - 1;
            m &= (m - 1);
            const int p = base + bit;
            acc = fmaxf(acc, values[p * C + lane]);  // coalesced 256B, L2-hit
        }
    }

    // ---- Phase 3: cross-wave reduction ----
    __shared__ float part[WAVES][C];
    part[w][lane] = acc;
    __syncthreads();
    if (w == 0) {
        const float r = fmaxf(fmaxf(part[0][lane], part[1][lane]),
                              fmaxf(part[2][lane], part[3][lane]));
        out[q * C + lane] = r;
    }
}

extern "C" void kernel_launch(void* const* d_in, const int* in_sizes, int n_in,
                              void* d_out, int out_size, void* d_ws, size_t ws_size,
                              hipStream_t stream) {
    const float* values  = (const float*)d_in[0];  // [4096, 64]
    const float* coords  = (const float*)d_in[1];  // [4096, 2]
    const float* qcoords = (const float*)d_in[2];  // [1024, 2]
    float* out = (float*)d_out;                    // [1024, 64]

    dim3 block(64, WAVES);
    maxpool_box_kernel<<<M, block, 0, stream>>>(values, coords, qcoords, out);
}

// Round 2
// 61.801 us; speedup vs baseline: 1.0597x; 1.0597x over previous
//
#include <hip/hip_runtime.h>

// Problem constants (match reference.py)
constexpr int N = 4096;   // points
constexpr int M = 1024;   // queries
constexpr int C = 64;     // channels
#define HALF_KW 0.05f     // kernel_size/2, strict '<' per reference
#define NEG_INF (-3.402823466e38f)   // jnp.finfo(float32).min == -FLT_MAX

// One block (256 thr = 4 waves) per query.
// Phase 1: compact in-box point indices into an LDS list.
//          coords read as float4 (2 points per lane per iter, 8 iters).
// Phase 2: gather in groups of 4 points: lane = (sub<<4)|cq where sub = point
//          in group, cq = channel quad -> each lane loads float4 of values
//          (16 B/lane, 1 KB per wave instruction). Groups round-robin over
//          the 4 waves (~3 group-loads each for ~41 expected hits).
//          List padded with a duplicate index (harmless under max).
// Phase 3: 16 partials per channel-quad reduced via LDS by threads 0..15.
__global__ __launch_bounds__(256) void maxpool_box_kernel(
    const float* __restrict__ values,    // [N, C]
    const float* __restrict__ coords,    // [N, 2]
    const float* __restrict__ qcoords,   // [M, 2]
    float* __restrict__ out)             // [M, C]
{
    __shared__ int    s_cnt;
    __shared__ int    s_list[N];          // worst-case all points match
    __shared__ float4 s_part[16][16];     // [w*4+sub][cq]

    const int q    = blockIdx.x;
    const int tid  = threadIdx.x;         // 0..255
    const int lane = tid & 63;
    const int w    = tid >> 6;            // wave id 0..3

    if (tid == 0) s_cnt = 0;
    __syncthreads();

    const float qx = qcoords[2 * q + 0];
    const float qy = qcoords[2 * q + 1];

    // ---- Phase 1: build compacted hit list ----
    const float4* c4p = (const float4*)coords;   // one float4 = coords of 2 points
    #pragma unroll
    for (int i = 0; i < N / (256 * 2); ++i) {    // 8 iters
        const int pair = i * 256 + tid;          // points 2*pair, 2*pair+1
        const float4 cc = c4p[pair];
        const bool in0 = (fabsf(qx - cc.x) < HALF_KW) && (fabsf(qy - cc.y) < HALF_KW);
        const bool in1 = (fabsf(qx - cc.z) < HALF_KW) && (fabsf(qy - cc.w) < HALF_KW);
        if (in0) { int k = atomicAdd(&s_cnt, 1); s_list[k] = 2 * pair; }
        if (in1) { int k = atomicAdd(&s_cnt, 1); s_list[k] = 2 * pair + 1; }
    }
    __syncthreads();

    const int cnt = s_cnt;
    const int G   = (cnt + 3) >> 2;              // groups of 4 points
    // pad list tail (at most 3 slots) with a duplicate index
    if (cnt > 0 && tid < G * 4 - cnt) s_list[cnt + tid] = s_list[0];
    __syncthreads();

    // ---- Phase 2: grouped float4 gather ----
    const int sub = lane >> 4;                   // point-in-group 0..3
    const int cq  = lane & 15;                   // channel quad 0..15
    const float4* v4 = (const float4*)values;    // [N][16] float4
    float4 acc = make_float4(NEG_INF, NEG_INF, NEG_INF, NEG_INF);
    for (int g = w; g < G; g += 4) {
        const int p = s_list[g * 4 + sub];       // LDS broadcast within 16 lanes
        const float4 v = v4[p * 16 + cq];        // coalesced 16 B/lane
        acc.x = fmaxf(acc.x, v.x);
        acc.y = fmaxf(acc.y, v.y);
        acc.z = fmaxf(acc.z, v.z);
        acc.w = fmaxf(acc.w, v.w);
    }
    s_part[w * 4 + sub][cq] = acc;
    __syncthreads();

    // ---- Phase 3: reduce 16 partials per channel quad, write out ----
    if (tid < 16) {
        float4 r = s_part[0][tid];
        #pragma unroll
        for (int k = 1; k < 16; ++k) {
            const float4 t = s_part[k][tid];
            r.x = fmaxf(r.x, t.x);
            r.y = fmaxf(r.y, t.y);
            r.z = fmaxf(r.z, t.z);
            r.w = fmaxf(r.w, t.w);
        }
        ((float4*)out)[q * 16 + tid] = r;
    }
}

extern "C" void kernel_launch(void* const* d_in, const int* in_sizes, int n_in,
                              void* d_out, int out_size, void* d_ws, size_t ws_size,
                              hipStream_t stream) {
    const float* values  = (const float*)d_in[0];  // [4096, 64]
    const float* coords  = (const float*)d_in[1];  // [4096, 2]
    const float* qcoords = (const float*)d_in[2];  // [1024, 2]
    float* out = (float*)d_out;                    // [1024, 64]

    maxpool_box_kernel<<<M, 256, 0, stream>>>(values, coords, qcoords, out);
}